// Round 10
// baseline (361.164 us; speedup 1.0000x reference)
//
#include <hip/hip_runtime.h>

typedef __attribute__((ext_vector_type(8))) short short8;
typedef __attribute__((ext_vector_type(4))) float f32x4;

#define HW 65536
#define NPOS 32768
#define NPOS2 16384

__device__ __forceinline__ unsigned short f2bf(float f) {
  unsigned u = __builtin_bit_cast(unsigned, f);
  u += 0x7fffu + ((u >> 16) & 1u);
  return (unsigned short)(u >> 16);
}
__device__ __forceinline__ float bf2f(unsigned short h) {
  unsigned u = (unsigned)h << 16;
  return __builtin_bit_cast(float, u);
}
__device__ __forceinline__ int slot4(int r) { return (r ^ (r >> 2)) & 15; }

// ---------------------------------------------------------------------------
// k0: split conv weights to bf16 hi/lo; rows 0-31 = phi, 32-63 = g.
// ---------------------------------------------------------------------------
__global__ __launch_bounds__(256) void k0_prep(
    const float* __restrict__ wphi, const float* __restrict__ wg,
    unsigned short* __restrict__ Whi, unsigned short* __restrict__ Wlo)
{
  const int idx = blockIdx.x * 256 + threadIdx.x;  // 4096 total
  const int u = idx >> 6, c = idx & 63;
  const float w = (u < 32) ? wphi[u * 64 + c] : wg[(u - 32) * 64 + c];
  const unsigned short h = f2bf(w);
  Whi[idx] = h;
  Wlo[idx] = f2bf(w - bf2f(h));
}

// ---------------------------------------------------------------------------
// k1: STREAMING conv+exp -> Ep, Eg (bf16, global, n-chunk of 16384) + sums.
// Grid (128, 8) per pass: blk>>6 = h, (blk&63)*256 = n-col base. 256 thr.
// Weights staged once to LDS (granule-XOR swizzle -> b128 reads at bank
// floor); x A-fragments direct from global, double-buffered; NO barriers
// after staging, no LDS E, no inter-wave coupling. E writes: 16 rows x 32B
// sectors per instr, lines completed by consecutive iters.
// ---------------------------------------------------------------------------
__global__ __launch_bounds__(256) void k1_conv(
    const float* __restrict__ x, const unsigned short* __restrict__ Whi,
    const unsigned short* __restrict__ Wlo, unsigned short* __restrict__ Ep,
    unsigned short* __restrict__ Eg, float* __restrict__ sums, int n_off)
{
  __shared__ unsigned short Whs[4096], Wls[4096];
  const int tid = threadIdx.x;
  const int b = blockIdx.y, blk = blockIdx.x;
  const int w = tid >> 6, l = tid & 63;
  const int lr = l & 15, g = l >> 4;

  // stage swizzled weights (granule = 8 elems = 16B; swizzle granule^row&7)
  for (int gi = tid; gi < 512; gi += 256) {
    const int row = gi >> 3, gcol = gi & 7;
    const int d = row * 64 + ((gcol ^ (row & 7)) << 3);
    *(uint4*)&Whs[d] = *(const uint4*)(Whi + gi * 8);
    *(uint4*)&Wls[d] = *(const uint4*)(Wlo + gi * 8);
  }
  __syncthreads();   // the only barrier

  const int h = blk >> 6, bl = blk & 63;
  const int p0 = h * NPOS + n_off + bl * 256 + w * 64;
  const int nl0 = bl * 256 + w * 64;
  const float* xp = x + (size_t)b * 64 * HW + p0 + lr;
  unsigned short* EpB = Ep + (size_t)b * 64 * NPOS2;
  unsigned short* EgB = Eg + (size_t)b * 64 * NPOS2;

  float ssp = 0.f, ssg = 0.f;
  float xv0[16], xv1[16];
  #pragma unroll
  for (int e = 0; e < 16; ++e)
    xv0[e] = xp[(size_t)((e >> 3) * 32 + g * 8 + (e & 7)) * HW];

  #pragma unroll
  for (int it = 0; it < 4; ++it) {
    const float* cur = (it & 1) ? xv1 : xv0;
    float* nxt = (it & 1) ? xv0 : xv1;
    if (it < 3) {
      #pragma unroll
      for (int e = 0; e < 16; ++e)
        nxt[e] = xp[(size_t)((e >> 3) * 32 + g * 8 + (e & 7)) * HW + (it + 1) * 16];
    }
    short8 ah[2];
    #pragma unroll
    for (int ks = 0; ks < 2; ++ks)
      #pragma unroll
      for (int e = 0; e < 8; ++e)
        ah[ks][e] = (short)f2bf(cur[ks * 8 + e]);
    const int ncol = nl0 + it * 16 + g * 4;
    #pragma unroll
    for (int cht = 0; cht < 4; ++cht) {
      const int wr = cht * 16 + lr;
      const int base = wr * 64, sw = wr & 7;
      const short8 wh0 = *(const short8*)&Whs[base + ((g ^ sw) << 3)];
      const short8 wl0 = *(const short8*)&Wls[base + ((g ^ sw) << 3)];
      const short8 wh1 = *(const short8*)&Whs[base + (((4 + g) ^ sw) << 3)];
      const short8 wl1 = *(const short8*)&Wls[base + (((4 + g) ^ sw) << 3)];
      f32x4 cacc = {0.f, 0.f, 0.f, 0.f};
      cacc = __builtin_amdgcn_mfma_f32_16x16x32_bf16(ah[0], wh0, cacc, 0, 0, 0);
      cacc = __builtin_amdgcn_mfma_f32_16x16x32_bf16(ah[0], wl0, cacc, 0, 0, 0);
      cacc = __builtin_amdgcn_mfma_f32_16x16x32_bf16(ah[1], wh1, cacc, 0, 0, 0);
      cacc = __builtin_amdgcn_mfma_f32_16x16x32_bf16(ah[1], wl1, cacc, 0, 0, 0);
      const float e0 = __expf(cacc[0]), e1 = __expf(cacc[1]);
      const float e2 = __expf(cacc[2]), e3 = __expf(cacc[3]);
      uint2 pk;
      pk.x = (unsigned)f2bf(e0) | ((unsigned)f2bf(e1) << 16);
      pk.y = (unsigned)f2bf(e2) | ((unsigned)f2bf(e3) << 16);
      const int row = 2 * ((cht & 1) * 16 + lr) + h;
      if (cht < 2) {
        ssp += (e0 + e1) + (e2 + e3);
        *(uint2*)&EpB[(size_t)row * NPOS2 + ncol] = pk;
      } else {
        ssg += (e0 + e1) + (e2 + e3);
        *(uint2*)&EgB[(size_t)row * NPOS2 + ncol] = pk;
      }
    }
  }
  #pragma unroll
  for (int off = 32; off > 0; off >>= 1) {
    ssp += __shfl_down(ssp, off);
    ssg += __shfl_down(ssg, off);
  }
  if (l == 0) {
    atomicAdd(&sums[b], ssp);
    atomicAdd(&sums[8 + b], ssg);
  }
}

// ---------------------------------------------------------------------------
// k2: att rank-K update: att[c][d] += sum_k Eg[c][k]*Ep[d][k], K-chunk = 256.
// Grid (64, 8) per pass. 256 thr = 4 waves; wave w: rows [16w,16w+16) vs all
// 64 cols. Operands direct from global (full 64B-line reads, L2/L3-warm).
// No LDS, no barriers. attP slot = b*128 + pass*64 + blk.
// ---------------------------------------------------------------------------
__global__ __launch_bounds__(256) void k2_att(
    const unsigned short* __restrict__ Ep, const unsigned short* __restrict__ Eg,
    float* __restrict__ attP, int pass)
{
  const int tid = threadIdx.x;
  const int b = blockIdx.y, blk = blockIdx.x;
  const int w = tid >> 6, l = tid & 63;
  const int lr = l & 15, g = l >> 4;
  const int k0 = blk * 256 + g * 8;
  const unsigned short* avp = Eg + (size_t)(b * 64 + w * 16 + lr) * NPOS2 + k0;
  const unsigned short* bpb = Ep + (size_t)b * 64 * NPOS2 + k0;

  f32x4 aacc[4] = {{0.f,0.f,0.f,0.f},{0.f,0.f,0.f,0.f},{0.f,0.f,0.f,0.f},{0.f,0.f,0.f,0.f}};
  #pragma unroll
  for (int ks = 0; ks < 8; ++ks) {
    const short8 av = *(const short8*)(avp + ks * 32);
    #pragma unroll
    for (int j = 0; j < 4; ++j) {
      const short8 bv = *(const short8*)(bpb + (size_t)(j * 16 + lr) * NPOS2 + ks * 32);
      aacc[j] = __builtin_amdgcn_mfma_f32_16x16x32_bf16(av, bv, aacc[j], 0, 0, 0);
    }
  }
  float* ap = attP + (size_t)(b * 128 + pass * 64 + blk) * 4096;
  #pragma unroll
  for (int j = 0; j < 4; ++j)
    #pragma unroll
    for (int r = 0; r < 4; ++r)
      ap[(w * 16 + g * 4 + r) * 64 + j * 16 + lr] = aacc[j][r];
}

// ---------------------------------------------------------------------------
// k3a: partial-reduce att partials 128 -> 8 per batch. Grid (64).
// ---------------------------------------------------------------------------
__global__ __launch_bounds__(256) void k3a_reduce(
    const float* __restrict__ attP, float* __restrict__ attQ)
{
  const int b = blockIdx.x >> 3, part = blockIdx.x & 7;
  const float* p = attP + (size_t)(b * 128 + part * 16) * 4096;
  float* q = attQ + (size_t)(b * 8 + part) * 4096;
  for (int e = threadIdx.x; e < 4096; e += 256) {
    float s0 = 0.f, s1 = 0.f, s2 = 0.f, s3 = 0.f;
    #pragma unroll
    for (int k = 0; k < 16; k += 4) {
      s0 += p[(size_t)k * 4096 + e];
      s1 += p[(size_t)(k + 1) * 4096 + e];
      s2 += p[(size_t)(k + 2) * 4096 + e];
      s3 += p[(size_t)(k + 3) * 4096 + e];
    }
    q[e] = (s0 + s1) + (s2 + s3);
  }
}

// ---------------------------------------------------------------------------
// k3b: final reduce + N[b][oo=h*64+o][cc=e*64+c] =
//      scale * sum_j ( sum_i wm[o][i]*att[2i+h][2j+e] ) * Wth[j][c] -> bf16 hi/lo
// ---------------------------------------------------------------------------
__global__ __launch_bounds__(1024) void k3b_nmat(
    const float* __restrict__ attQ, const float* __restrict__ sums,
    const float* __restrict__ wm, const float* __restrict__ wtheta,
    unsigned short* __restrict__ Nhi, unsigned short* __restrict__ Nlo)
{
  __shared__ float att_s[4096];
  __shared__ float Mp[2][64][64];
  __shared__ float wms[64][32];
  __shared__ float wts[32][64];
  const int tid = threadIdx.x;
  const int b = blockIdx.x;

  if (tid < 512) {
    if (tid < 256) { for (int k = tid; k < 2048; k += 256) wms[k >> 5][k & 31] = wm[k]; }
    else           { for (int k = tid - 256; k < 2048; k += 256) wts[k >> 6][k & 63] = wtheta[k]; }
  }
  for (int e = tid; e < 4096; e += 1024) {
    const float* p = attQ + (size_t)b * 8 * 4096 + e;
    float s = 0.f;
    #pragma unroll
    for (int q = 0; q < 8; ++q) s += p[(size_t)q * 4096];
    att_s[e] = s;
  }
  __syncthreads();
  for (int idx = tid; idx < 8192; idx += 1024) {
    const int h = idx >> 12, o = (idx >> 6) & 63, d = idx & 63;
    float s = 0.f;
    #pragma unroll
    for (int i = 0; i < 32; ++i)
      s = __builtin_fmaf(wms[o][i], att_s[(2 * i + h) * 64 + d], s);
    Mp[h][o][d] = s;
  }
  __syncthreads();
  const float scale = 1.f / (sums[b] * sums[8 + b]);
  for (int idx = tid; idx < 16384; idx += 1024) {
    const int oo = idx >> 7, cc = idx & 127;
    const int h = oo >> 6, o = oo & 63, e = cc >> 6, c = cc & 63;
    float s = 0.f;
    #pragma unroll
    for (int j = 0; j < 32; ++j)
      s = __builtin_fmaf(Mp[h][o][2 * j + e], wts[j][c], s);
    s *= scale;
    const unsigned short hi = f2bf(s);
    Nhi[(size_t)b * 16384 + idx] = hi;
    Nlo[(size_t)b * 16384 + idx] = f2bf(s - bf2f(hi));
  }
}

// ---------------------------------------------------------------------------
// k5: out[b][o][h*NPOS+n] = sum_cc N[b][h*64+o][cc] * x[b][cc&63][(cc>>6)*NPOS+n]
// A = x [n][cc], B = N rows (oo) -> lane stores float4 of consecutive n.
// ---------------------------------------------------------------------------
__global__ __launch_bounds__(512) void k5_out(
    const float* __restrict__ x, const unsigned short* __restrict__ Nhi,
    const unsigned short* __restrict__ Nlo, float* __restrict__ out)
{
  __shared__ unsigned short Xh[64 * 128];   // [n][cc] bf16, cc ^ (slot4(n)<<3)
  const int tid = threadIdx.x;
  const int b = blockIdx.y, n0 = blockIdx.x * 64;
  const int w = tid >> 6, l = tid & 63;
  const int lr = l & 15, g = l >> 4;

  // B-fragments: N rows oo = w*16 + lr, K=128 (4 ksteps), hi/lo
  short8 bh[4], bl[4];
  #pragma unroll
  for (int ks = 0; ks < 4; ++ks) {
    const size_t off = (size_t)b * 16384 + (size_t)(w * 16 + lr) * 128 + ks * 32 + g * 8;
    bh[ks] = *(const short8*)(Nhi + off);
    bl[ks] = *(const short8*)(Nlo + off);
  }

  // stage X tile [n][cc]: wave w owns cc in [w*16, w*16+16); lane spans n
  {
    const int ccb = w * 16;
    const int c0 = ccb & 63, e0 = ccb >> 6;
    const float* xp = x + (size_t)b * 64 * HW + (size_t)c0 * HW
                    + (size_t)e0 * NPOS + n0 + l;
    float v[16];
    #pragma unroll
    for (int i = 0; i < 16; ++i) v[i] = xp[(size_t)i * HW];
    short8 pa, pb;
    #pragma unroll
    for (int i = 0; i < 8; ++i) {
      pa[i] = (short)f2bf(v[i]);
      pb[i] = (short)f2bf(v[8 + i]);
    }
    const int s8 = slot4(l) << 3;
    *(short8*)&Xh[l * 128 + (ccb ^ s8)] = pa;
    *(short8*)&Xh[l * 128 + ((ccb + 8) ^ s8)] = pb;
  }
  __syncthreads();

  const int oo = w * 16 + lr;   // this lane's output row (D col = lr)
  float* op = out + (size_t)b * 64 * HW + (size_t)(oo & 63) * HW
            + (size_t)(oo >> 6) * NPOS + n0 + g * 4;

  #pragma unroll
  for (int ct4 = 0; ct4 < 4; ++ct4) {
    f32x4 acc = {0.f, 0.f, 0.f, 0.f};
    const int arow = ct4 * 16 + lr;
    const int sw = slot4(arow) << 3;
    #pragma unroll
    for (int ks = 0; ks < 4; ++ks) {
      const short8 av = *(const short8*)&Xh[arow * 128 + ((ks * 32 + g * 8) ^ sw)];
      acc = __builtin_amdgcn_mfma_f32_16x16x32_bf16(av, bh[ks], acc, 0, 0, 0);
      acc = __builtin_amdgcn_mfma_f32_16x16x32_bf16(av, bl[ks], acc, 0, 0, 0);
    }
    *(float4*)(op + ct4 * 16) = *(float4*)&acc;
  }
}

// ---------------------------------------------------------------------------
extern "C" void kernel_launch(void* const* d_in, const int* in_sizes, int n_in,
                              void* d_out, int out_size, void* d_ws, size_t ws_size,
                              hipStream_t stream)
{
  const float* x      = (const float*)d_in[0];
  const float* wphi   = (const float*)d_in[1];
  const float* wtheta = (const float*)d_in[2];
  const float* wg     = (const float*)d_in[3];
  const float* wm     = (const float*)d_in[4];
  float* out = (float*)d_out;

  char* ws = (char*)d_ws;
  float* attP         = (float*)ws;                                 // 16,777,216 B
  unsigned short* Whi = (unsigned short*)(ws + 16777216);           //      8,192 B
  unsigned short* Wlo = (unsigned short*)(ws + 16785408);           //      8,192 B
  unsigned short* Nhi = (unsigned short*)(ws + 16793600);           //    262,144 B
  unsigned short* Nlo = (unsigned short*)(ws + 17055744);           //    262,144 B
  float* sums         = (float*)(ws + 17317888);                    //         64 B
  float* attQ         = (float*)(ws + 17317952);                    //  1,048,576 B
  unsigned short* Ep  = (unsigned short*)(ws + 18366528);           // 16,777,216 B
  unsigned short* Eg  = (unsigned short*)(ws + 35143744);           // 16,777,216 B
                                                                    // total ~51.9 MB

  hipMemsetAsync(sums, 0, 64, stream);
  k0_prep<<<dim3(16), 256, 0, stream>>>(wphi, wg, Whi, Wlo);
  for (int pass = 0; pass < 2; ++pass) {
    k1_conv<<<dim3(128, 8), 256, 0, stream>>>(x, Whi, Wlo, Ep, Eg, sums, pass * NPOS2);
    k2_att<<<dim3(64, 8), 256, 0, stream>>>(Ep, Eg, attP, pass);
  }
  k3a_reduce<<<dim3(64), 256, 0, stream>>>(attP, attQ);
  k3b_nmat<<<dim3(8), 1024, 0, stream>>>(attQ, sums, wm, wtheta, Nhi, Nlo);
  k5_out<<<dim3(512, 8), 512, 0, stream>>>(x, Nhi, Nlo, out);
}

// Round 11
// 162.537 us; speedup vs baseline: 2.2220x; 2.2220x over previous
//
#include <hip/hip_runtime.h>

typedef __attribute__((ext_vector_type(8))) short short8;
typedef __attribute__((ext_vector_type(4))) float f32x4;

#define HW 65536
#define NPOS 32768
#define NPOS2 16384

__device__ __forceinline__ unsigned short f2bf(float f) {
  unsigned u = __builtin_bit_cast(unsigned, f);
  u += 0x7fffu + ((u >> 16) & 1u);
  return (unsigned short)(u >> 16);
}
__device__ __forceinline__ float bf2f(unsigned short h) {
  unsigned u = (unsigned)h << 16;
  return __builtin_bit_cast(float, u);
}
__device__ __forceinline__ int slot4(int r) { return (r ^ (r >> 2)) & 15; }

// ---------------------------------------------------------------------------
// k0: split conv weights to bf16 hi/lo; rows 0-31 = phi, 32-63 = g.
// ---------------------------------------------------------------------------
__global__ __launch_bounds__(256) void k0_prep(
    const float* __restrict__ wphi, const float* __restrict__ wg,
    unsigned short* __restrict__ Whi, unsigned short* __restrict__ Wlo)
{
  const int idx = blockIdx.x * 256 + threadIdx.x;  // 4096 total
  const int u = idx >> 6, c = idx & 63;
  const float w = (u < 32) ? wphi[u * 64 + c] : wg[(u - 32) * 64 + c];
  const unsigned short h = f2bf(w);
  Whi[idx] = h;
  Wlo[idx] = f2bf(w - bf2f(h));
}

// ---------------------------------------------------------------------------
// k1: conv+exp -> Ep/Eg (global bf16), NO ATOMICS (per-block spart slots).
// k5-proven skeleton: grid (256,8)/pass, 512 thr = 8 waves, block owns 64
// view-cols. Xh[64][128] staged like k5; weights in swizzled LDS; wave w =
// (h=w>>2, pos-tile pt=w&3): 2 LDS A-frags, 16 MFMA, 16 exp, 4 uint2 stores.
// Block softmax-sums: wave shfl-reduce -> LDS -> tid0 writes spart slot.
// ---------------------------------------------------------------------------
__global__ __launch_bounds__(512) void k1_conv(
    const float* __restrict__ x, const unsigned short* __restrict__ Whi,
    const unsigned short* __restrict__ Wlo, unsigned short* __restrict__ Ep,
    unsigned short* __restrict__ Eg, float2* __restrict__ spart,
    int n_off, int pass)
{
  __shared__ unsigned short Xh[64 * 128];        // [n][cc], cc ^ (slot4(n)<<3)
  __shared__ unsigned short Whs[4096], Wls[4096];
  __shared__ float2 rbuf[8];
  const int tid = threadIdx.x;
  const int b = blockIdx.y, blk = blockIdx.x;
  const int w = tid >> 6, l = tid & 63;
  const int lr = l & 15, g = l >> 4;
  const float* xb = x + (size_t)b * 64 * HW;

  // stage swizzled weights (granule = 8 elems = 16B; phys granule = log ^ row&7)
  {
    const int gi = tid;   // 512 granules, one per thread
    const int row = gi >> 3, gcol = gi & 7;
    const int d = row * 64 + ((gcol ^ (row & 7)) << 3);
    *(uint4*)&Whs[d] = *(const uint4*)(Whi + gi * 8);
    *(uint4*)&Wls[d] = *(const uint4*)(Wlo + gi * 8);
  }

  // stage Xh exactly like k5: wave w owns cc in [w*16, w*16+16); lane spans n
  {
    const int ccb = w * 16;
    const int c0 = ccb & 63, e0 = ccb >> 6;
    const float* xp = xb + (size_t)c0 * HW + (size_t)e0 * NPOS
                    + n_off + blk * 64 + l;
    float v[16];
    #pragma unroll
    for (int i = 0; i < 16; ++i) v[i] = xp[(size_t)i * HW];
    short8 pa, pb;
    #pragma unroll
    for (int i = 0; i < 8; ++i) {
      pa[i] = (short)f2bf(v[i]);
      pb[i] = (short)f2bf(v[8 + i]);
    }
    const int s8 = slot4(l) << 3;
    *(short8*)&Xh[l * 128 + (ccb ^ s8)] = pa;
    *(short8*)&Xh[l * 128 + ((ccb + 8) ^ s8)] = pb;
  }
  __syncthreads();

  const int h = w >> 2, pt = w & 3;
  // A-fragments: rows pos = pt*16+lr, k = c (this h's channels)
  short8 ax[2];
  #pragma unroll
  for (int ks = 0; ks < 2; ++ks) {
    const int arow = pt * 16 + lr;
    ax[ks] = *(const short8*)&Xh[arow * 128
            + ((h * 64 + ks * 32 + g * 8) ^ (slot4(arow) << 3))];
  }

  float ssp = 0.f, ssg = 0.f;
  unsigned short* EpB = Ep + (size_t)b * 64 * NPOS2;
  unsigned short* EgB = Eg + (size_t)b * 64 * NPOS2;
  const int ncol = blk * 64 + pt * 16 + g * 4;

  #pragma unroll
  for (int cht = 0; cht < 4; ++cht) {
    const int wr = cht * 16 + lr;
    const int base = wr * 64, sw = wr & 7;
    const short8 wh0 = *(const short8*)&Whs[base + ((g ^ sw) << 3)];
    const short8 wl0 = *(const short8*)&Wls[base + ((g ^ sw) << 3)];
    const short8 wh1 = *(const short8*)&Whs[base + (((4 + g) ^ sw) << 3)];
    const short8 wl1 = *(const short8*)&Wls[base + (((4 + g) ^ sw) << 3)];
    f32x4 cacc = {0.f, 0.f, 0.f, 0.f};
    cacc = __builtin_amdgcn_mfma_f32_16x16x32_bf16(ax[0], wh0, cacc, 0, 0, 0);
    cacc = __builtin_amdgcn_mfma_f32_16x16x32_bf16(ax[0], wl0, cacc, 0, 0, 0);
    cacc = __builtin_amdgcn_mfma_f32_16x16x32_bf16(ax[1], wh1, cacc, 0, 0, 0);
    cacc = __builtin_amdgcn_mfma_f32_16x16x32_bf16(ax[1], wl1, cacc, 0, 0, 0);
    const float e0 = __expf(cacc[0]), e1 = __expf(cacc[1]);
    const float e2 = __expf(cacc[2]), e3 = __expf(cacc[3]);
    uint2 pk;
    pk.x = (unsigned)f2bf(e0) | ((unsigned)f2bf(e1) << 16);
    pk.y = (unsigned)f2bf(e2) | ((unsigned)f2bf(e3) << 16);
    const int row = 2 * ((cht & 1) * 16 + lr) + h;
    if (cht < 2) {
      ssp += (e0 + e1) + (e2 + e3);
      *(uint2*)&EpB[(size_t)row * NPOS2 + ncol] = pk;
    } else {
      ssg += (e0 + e1) + (e2 + e3);
      *(uint2*)&EgB[(size_t)row * NPOS2 + ncol] = pk;
    }
  }

  // block-level sums, NO global atomics
  #pragma unroll
  for (int off = 32; off > 0; off >>= 1) {
    ssp += __shfl_down(ssp, off);
    ssg += __shfl_down(ssg, off);
  }
  if (l == 0) rbuf[w] = make_float2(ssp, ssg);
  __syncthreads();
  if (tid == 0) {
    float a = 0.f, c = 0.f;
    #pragma unroll
    for (int i = 0; i < 8; ++i) { a += rbuf[i].x; c += rbuf[i].y; }
    spart[pass * 2048 + b * 256 + blk] = make_float2(a, c);
  }
}

// ---------------------------------------------------------------------------
// k2: att rank-K update: att[c][d] += sum_k Eg[c][k]*Ep[d][k], K-chunk = 256.
// Grid (64, 8) per pass. No LDS, no barriers, no atomics.
// ---------------------------------------------------------------------------
__global__ __launch_bounds__(256) void k2_att(
    const unsigned short* __restrict__ Ep, const unsigned short* __restrict__ Eg,
    float* __restrict__ attP, int pass)
{
  const int tid = threadIdx.x;
  const int b = blockIdx.y, blk = blockIdx.x;
  const int w = tid >> 6, l = tid & 63;
  const int lr = l & 15, g = l >> 4;
  const int k0 = blk * 256 + g * 8;
  const unsigned short* avp = Eg + (size_t)(b * 64 + w * 16 + lr) * NPOS2 + k0;
  const unsigned short* bpb = Ep + (size_t)b * 64 * NPOS2 + k0;

  f32x4 aacc[4] = {{0.f,0.f,0.f,0.f},{0.f,0.f,0.f,0.f},{0.f,0.f,0.f,0.f},{0.f,0.f,0.f,0.f}};
  #pragma unroll
  for (int ks = 0; ks < 8; ++ks) {
    const short8 av = *(const short8*)(avp + ks * 32);
    #pragma unroll
    for (int j = 0; j < 4; ++j) {
      const short8 bv = *(const short8*)(bpb + (size_t)(j * 16 + lr) * NPOS2 + ks * 32);
      aacc[j] = __builtin_amdgcn_mfma_f32_16x16x32_bf16(av, bv, aacc[j], 0, 0, 0);
    }
  }
  float* ap = attP + (size_t)(b * 128 + pass * 64 + blk) * 4096;
  #pragma unroll
  for (int j = 0; j < 4; ++j)
    #pragma unroll
    for (int r = 0; r < 4; ++r)
      ap[(w * 16 + g * 4 + r) * 64 + j * 16 + lr] = aacc[j][r];
}

// ---------------------------------------------------------------------------
// k3a: partial-reduce att partials 128 -> 8 per batch. Grid (64).
// ---------------------------------------------------------------------------
__global__ __launch_bounds__(256) void k3a_reduce(
    const float* __restrict__ attP, float* __restrict__ attQ)
{
  const int b = blockIdx.x >> 3, part = blockIdx.x & 7;
  const float* p = attP + (size_t)(b * 128 + part * 16) * 4096;
  float* q = attQ + (size_t)(b * 8 + part) * 4096;
  for (int e = threadIdx.x; e < 4096; e += 256) {
    float s0 = 0.f, s1 = 0.f, s2 = 0.f, s3 = 0.f;
    #pragma unroll
    for (int k = 0; k < 16; k += 4) {
      s0 += p[(size_t)k * 4096 + e];
      s1 += p[(size_t)(k + 1) * 4096 + e];
      s2 += p[(size_t)(k + 2) * 4096 + e];
      s3 += p[(size_t)(k + 3) * 4096 + e];
    }
    q[e] = (s0 + s1) + (s2 + s3);
  }
}

// ---------------------------------------------------------------------------
// k3b: reduce spart (512 float2/batch) -> scale; final att reduce; N mats.
// ---------------------------------------------------------------------------
__global__ __launch_bounds__(1024) void k3b_nmat(
    const float* __restrict__ attQ, const float2* __restrict__ spart,
    const float* __restrict__ wm, const float* __restrict__ wtheta,
    unsigned short* __restrict__ Nhi, unsigned short* __restrict__ Nlo)
{
  __shared__ float att_s[4096];
  __shared__ float Mp[2][64][64];
  __shared__ float wms[64][32];
  __shared__ float wts[32][64];
  __shared__ float sP[512], sG[512];
  const int tid = threadIdx.x;
  const int b = blockIdx.x;

  if (tid < 512) {
    const int pass = tid >> 8, blk = tid & 255;
    const float2 v = spart[pass * 2048 + b * 256 + blk];
    sP[tid] = v.x; sG[tid] = v.y;
    if (tid < 256) { for (int k = tid; k < 2048; k += 256) wms[k >> 5][k & 31] = wm[k]; }
    else           { for (int k = tid - 256; k < 2048; k += 256) wts[k >> 6][k & 63] = wtheta[k]; }
  }
  for (int e = tid; e < 4096; e += 1024) {
    const float* p = attQ + (size_t)b * 8 * 4096 + e;
    float s = 0.f;
    #pragma unroll
    for (int q = 0; q < 8; ++q) s += p[(size_t)q * 4096];
    att_s[e] = s;
  }
  __syncthreads();
  #pragma unroll
  for (int s = 256; s > 0; s >>= 1) {
    if (tid < s) { sP[tid] += sP[tid + s]; sG[tid] += sG[tid + s]; }
    __syncthreads();
  }
  for (int idx = tid; idx < 8192; idx += 1024) {
    const int h = idx >> 12, o = (idx >> 6) & 63, d = idx & 63;
    float s = 0.f;
    #pragma unroll
    for (int i = 0; i < 32; ++i)
      s = __builtin_fmaf(wms[o][i], att_s[(2 * i + h) * 64 + d], s);
    Mp[h][o][d] = s;
  }
  __syncthreads();
  const float scale = 1.f / (sP[0] * sG[0]);
  for (int idx = tid; idx < 16384; idx += 1024) {
    const int oo = idx >> 7, cc = idx & 127;
    const int h = oo >> 6, o = oo & 63, e = cc >> 6, c = cc & 63;
    float s = 0.f;
    #pragma unroll
    for (int j = 0; j < 32; ++j)
      s = __builtin_fmaf(Mp[h][o][2 * j + e], wts[j][c], s);
    s *= scale;
    const unsigned short hi = f2bf(s);
    Nhi[(size_t)b * 16384 + idx] = hi;
    Nlo[(size_t)b * 16384 + idx] = f2bf(s - bf2f(hi));
  }
}

// ---------------------------------------------------------------------------
// k5: out[b][o][h*NPOS+n] = sum_cc N[b][h*64+o][cc] * x[b][cc&63][(cc>>6)*NPOS+n]
// A = x [n][cc], B = N rows (oo) -> lane stores float4 of consecutive n.
// ---------------------------------------------------------------------------
__global__ __launch_bounds__(512) void k5_out(
    const float* __restrict__ x, const unsigned short* __restrict__ Nhi,
    const unsigned short* __restrict__ Nlo, float* __restrict__ out)
{
  __shared__ unsigned short Xh[64 * 128];   // [n][cc] bf16, cc ^ (slot4(n)<<3)
  const int tid = threadIdx.x;
  const int b = blockIdx.y, n0 = blockIdx.x * 64;
  const int w = tid >> 6, l = tid & 63;
  const int lr = l & 15, g = l >> 4;

  short8 bh[4], bl[4];
  #pragma unroll
  for (int ks = 0; ks < 4; ++ks) {
    const size_t off = (size_t)b * 16384 + (size_t)(w * 16 + lr) * 128 + ks * 32 + g * 8;
    bh[ks] = *(const short8*)(Nhi + off);
    bl[ks] = *(const short8*)(Nlo + off);
  }

  {
    const int ccb = w * 16;
    const int c0 = ccb & 63, e0 = ccb >> 6;
    const float* xp = x + (size_t)b * 64 * HW + (size_t)c0 * HW
                    + (size_t)e0 * NPOS + n0 + l;
    float v[16];
    #pragma unroll
    for (int i = 0; i < 16; ++i) v[i] = xp[(size_t)i * HW];
    short8 pa, pb;
    #pragma unroll
    for (int i = 0; i < 8; ++i) {
      pa[i] = (short)f2bf(v[i]);
      pb[i] = (short)f2bf(v[8 + i]);
    }
    const int s8 = slot4(l) << 3;
    *(short8*)&Xh[l * 128 + (ccb ^ s8)] = pa;
    *(short8*)&Xh[l * 128 + ((ccb + 8) ^ s8)] = pb;
  }
  __syncthreads();

  const int oo = w * 16 + lr;
  float* op = out + (size_t)b * 64 * HW + (size_t)(oo & 63) * HW
            + (size_t)(oo >> 6) * NPOS + n0 + g * 4;

  #pragma unroll
  for (int ct4 = 0; ct4 < 4; ++ct4) {
    f32x4 acc = {0.f, 0.f, 0.f, 0.f};
    const int arow = ct4 * 16 + lr;
    const int sw = slot4(arow) << 3;
    #pragma unroll
    for (int ks = 0; ks < 4; ++ks) {
      const short8 av = *(const short8*)&Xh[arow * 128 + ((ks * 32 + g * 8) ^ sw)];
      acc = __builtin_amdgcn_mfma_f32_16x16x32_bf16(av, bh[ks], acc, 0, 0, 0);
      acc = __builtin_amdgcn_mfma_f32_16x16x32_bf16(av, bl[ks], acc, 0, 0, 0);
    }
    *(float4*)(op + ct4 * 16) = *(float4*)&acc;
  }
}

// ---------------------------------------------------------------------------
extern "C" void kernel_launch(void* const* d_in, const int* in_sizes, int n_in,
                              void* d_out, int out_size, void* d_ws, size_t ws_size,
                              hipStream_t stream)
{
  const float* x      = (const float*)d_in[0];
  const float* wphi   = (const float*)d_in[1];
  const float* wtheta = (const float*)d_in[2];
  const float* wg     = (const float*)d_in[3];
  const float* wm     = (const float*)d_in[4];
  float* out = (float*)d_out;

  char* ws = (char*)d_ws;
  float* attP         = (float*)ws;                                 // 16,777,216 B
  unsigned short* Whi = (unsigned short*)(ws + 16777216);           //      8,192 B
  unsigned short* Wlo = (unsigned short*)(ws + 16785408);           //      8,192 B
  unsigned short* Nhi = (unsigned short*)(ws + 16793600);           //    262,144 B
  unsigned short* Nlo = (unsigned short*)(ws + 17055744);           //    262,144 B
  float2* spart       = (float2*)(ws + 17317888);                   //     32,768 B
  float* attQ         = (float*)(ws + 17350656);                    //  1,048,576 B
  unsigned short* Ep  = (unsigned short*)(ws + 18399232);           // 16,777,216 B
  unsigned short* Eg  = (unsigned short*)(ws + 35176448);           // 16,777,216 B

  k0_prep<<<dim3(16), 256, 0, stream>>>(wphi, wg, Whi, Wlo);
  for (int pass = 0; pass < 2; ++pass) {
    k1_conv<<<dim3(256, 8), 512, 0, stream>>>(x, Whi, Wlo, Ep, Eg, spart,
                                              pass * NPOS2, pass);
    k2_att<<<dim3(64, 8), 256, 0, stream>>>(Ep, Eg, attP, pass);
  }
  k3a_reduce<<<dim3(64), 256, 0, stream>>>(attP, attQ);
  k3b_nmat<<<dim3(8), 1024, 0, stream>>>(attQ, spart, wm, wtheta, Nhi, Nlo);
  k5_out<<<dim3(512, 8), 512, 0, stream>>>(x, Nhi, Nlo, out);
}

// Round 12
// 125.229 us; speedup vs baseline: 2.8840x; 1.2979x over previous
//
#include <hip/hip_runtime.h>

typedef __attribute__((ext_vector_type(8))) short short8;
typedef __attribute__((ext_vector_type(4))) float f32x4;
typedef __attribute__((ext_vector_type(4))) unsigned int uint4v;

#define HW 65536
#define NPOS 32768

__device__ __forceinline__ unsigned short f2bf(float f) {
  unsigned u = __builtin_bit_cast(unsigned, f);
  u += 0x7fffu + ((u >> 16) & 1u);
  return (unsigned short)(u >> 16);
}
__device__ __forceinline__ float bf2f(unsigned short h) {
  unsigned u = (unsigned)h << 16;
  return __builtin_bit_cast(float, u);
}
__device__ __forceinline__ int slot4(int r) { return (r ^ (r >> 2)) & 15; }
// 16B fragment from 8B-aligned LDS (row stride 136B) as two b64 reads
__device__ __forceinline__ short8 ld_e16(const unsigned short* p) {
  const uint2 a = *(const uint2*)p;
  const uint2 b = *(const uint2*)(p + 4);
  uint4v u = {a.x, a.y, b.x, b.y};
  return __builtin_bit_cast(short8, u);
}

// ---------------------------------------------------------------------------
// k0: split conv weights to bf16 hi/lo; rows 0-31 = phi, 32-63 = g.
// ---------------------------------------------------------------------------
__global__ __launch_bounds__(256) void k0_prep(
    const float* __restrict__ wphi, const float* __restrict__ wg,
    unsigned short* __restrict__ Whi, unsigned short* __restrict__ Wlo)
{
  const int idx = blockIdx.x * 256 + threadIdx.x;  // 4096 total
  const int u = idx >> 6, c = idx & 63;
  const float w = (u < 32) ? wphi[u * 64 + c] : wg[(u - 32) * 64 + c];
  const unsigned short h = f2bf(w);
  Whi[idx] = h;
  Wlo[idx] = f2bf(w - bf2f(h));
}

// ---------------------------------------------------------------------------
// k1: FUSED conv (A = x direct global, B = W hi/lo) + exp + att (cooperative).
// R9 structure verbatim, minus global atomics (per-block spart slot instead —
// the R3-R10 ~130µs floor was ~8k same-line atomicAdds, not the barriers).
// Grid (128, 8). Block = 4 waves / 256 thr, owns 256 view-cols = 4 subtiles.
// E double-buffered in LDS, ONE barrier/subtile, E never touches global.
// ---------------------------------------------------------------------------
__global__ __launch_bounds__(256) void k1_att(
    const float* __restrict__ x, const unsigned short* __restrict__ Whi,
    const unsigned short* __restrict__ Wlo, float* __restrict__ attP,
    float2* __restrict__ spart)
{
  __shared__ unsigned short E[2][128 * 68];   // [buf][row][68]; rows 0-63 Ep, 64-127 Eg
  __shared__ float2 rbuf[4];

  const int tid = threadIdx.x;
  const int b = blockIdx.y, blk = blockIdx.x;
  const int w = tid >> 6, l = tid & 63;
  const int lr = l & 15, g = l >> 4;
  const int h = w >> 1, qb = (w & 1) * 2;     // conv: half h, quarters qb, qb+1
  const int n0 = blk * 256;
  const float* xb = x + (size_t)b * 64 * HW + (size_t)h * NPOS;

  // conv B-fragments (weights, hi/lo): [ch-tile][kstep]
  short8 wbh[4][2], wbl[4][2];
  #pragma unroll
  for (int cht = 0; cht < 4; ++cht)
    #pragma unroll
    for (int ks = 0; ks < 2; ++ks) {
      const size_t off = (size_t)(cht * 16 + lr) * 64 + ks * 32 + g * 8;
      wbh[cht][ks] = *(const short8*)(Whi + off);
      wbl[cht][ks] = *(const short8*)(Wlo + off);
    }

  f32x4 aacc[4] = {{0.f,0.f,0.f,0.f},{0.f,0.f,0.f,0.f},{0.f,0.f,0.f,0.f},{0.f,0.f,0.f,0.f}};
  float ssp = 0.f, ssg = 0.f;

  // A-fragment loads: lane (lr,g), element e -> channel (e>>3)*32+g*8+(e&7),
  // pos = base + lr (16 consecutive cols per 16-lane group: coalesced)
  float xvA[16], xvB[16];
  #pragma unroll
  for (int e = 0; e < 16; ++e) {
    const size_t co = (size_t)((e >> 3) * 32 + g * 8 + (e & 7)) * HW;
    xvA[e] = xb[co + n0 + (qb + 0) * 16 + lr];
    xvB[e] = xb[co + n0 + (qb + 1) * 16 + lr];
  }

  for (int t = 0; t < 4; ++t) {
    const int buf = t & 1;
    // two pos-tiles: convert, conv-MFMA, exp, E write
    #pragma unroll
    for (int j = 0; j < 2; ++j) {
      const float* xv = j ? xvB : xvA;
      short8 ah[2];
      #pragma unroll
      for (int ks = 0; ks < 2; ++ks)
        #pragma unroll
        for (int e = 0; e < 8; ++e)
          ah[ks][e] = (short)f2bf(xv[ks * 8 + e]);
      f32x4 cacc[4] = {{0.f,0.f,0.f,0.f},{0.f,0.f,0.f,0.f},{0.f,0.f,0.f,0.f},{0.f,0.f,0.f,0.f}};
      #pragma unroll
      for (int cht = 0; cht < 4; ++cht)
        #pragma unroll
        for (int ks = 0; ks < 2; ++ks) {
          cacc[cht] = __builtin_amdgcn_mfma_f32_16x16x32_bf16(ah[ks], wbh[cht][ks], cacc[cht], 0, 0, 0);
          cacc[cht] = __builtin_amdgcn_mfma_f32_16x16x32_bf16(ah[ks], wbl[cht][ks], cacc[cht], 0, 0, 0);
        }
      // exp + E[buf] write: lane holds D[pos=g*4+r][ch=lr] -> row f(ch), 4 consec n
      #pragma unroll
      for (int cht = 0; cht < 4; ++cht) {
        const float e0 = __expf(cacc[cht][0]);
        const float e1 = __expf(cacc[cht][1]);
        const float e2 = __expf(cacc[cht][2]);
        const float e3 = __expf(cacc[cht][3]);
        if (cht < 2) ssp += (e0 + e1) + (e2 + e3);
        else         ssg += (e0 + e1) + (e2 + e3);
        const int row = ((cht >= 2) ? 64 : 0) + 2 * ((cht & 1) * 16 + lr) + h;
        uint2 pk;
        pk.x = (unsigned)f2bf(e0) | ((unsigned)f2bf(e1) << 16);
        pk.y = (unsigned)f2bf(e2) | ((unsigned)f2bf(e3) << 16);
        *(uint2*)&E[buf][row * 68 + (qb + j) * 16 + g * 4] = pk;
      }
    }
    // prefetch next subtile BEFORE the barrier (drain overlaps sibling-wait)
    if (t < 3) {
      const int nn = n0 + (t + 1) * 64;
      #pragma unroll
      for (int e = 0; e < 16; ++e) {
        const size_t co = (size_t)((e >> 3) * 32 + g * 8 + (e & 7)) * HW;
        xvA[e] = xb[co + nn + (qb + 0) * 16 + lr];
        xvB[e] = xb[co + nn + (qb + 1) * 16 + lr];
      }
    }
    __syncthreads();   // E[buf] complete; E[buf^1] readers (t-1) done

    // att: wave owns row-block w vs col-blocks 0..3, K=64 (2 ksteps)
    #pragma unroll
    for (int ks = 0; ks < 2; ++ks) {
      const short8 ag = ld_e16(&E[buf][(64 + w * 16 + lr) * 68 + ks * 32 + g * 8]);
      #pragma unroll
      for (int j = 0; j < 4; ++j) {
        const short8 bp = ld_e16(&E[buf][(j * 16 + lr) * 68 + ks * 32 + g * 8]);
        aacc[j] = __builtin_amdgcn_mfma_f32_16x16x32_bf16(ag, bp, aacc[j], 0, 0, 0);
      }
    }
  }

  // flush att partials: lane holds att[w*16+g*4+r][j*16+lr]
  float* ap = attP + (size_t)(b * 128 + blk) * 4096;
  #pragma unroll
  for (int j = 0; j < 4; ++j)
    #pragma unroll
    for (int r = 0; r < 4; ++r)
      ap[(w * 16 + g * 4 + r) * 64 + j * 16 + lr] = aacc[j][r];

  // softmax denominators -> per-block slot (NO atomics)
  #pragma unroll
  for (int off = 32; off > 0; off >>= 1) {
    ssp += __shfl_down(ssp, off);
    ssg += __shfl_down(ssg, off);
  }
  if (l == 0) rbuf[w] = make_float2(ssp, ssg);
  __syncthreads();
  if (tid == 0) {
    float a = 0.f, c = 0.f;
    #pragma unroll
    for (int i = 0; i < 4; ++i) { a += rbuf[i].x; c += rbuf[i].y; }
    spart[b * 128 + blk] = make_float2(a, c);
  }
}

// ---------------------------------------------------------------------------
// k3a: partial-reduce att partials 128 -> 8 per batch. Grid (64).
// ---------------------------------------------------------------------------
__global__ __launch_bounds__(256) void k3a_reduce(
    const float* __restrict__ attP, float* __restrict__ attQ)
{
  const int b = blockIdx.x >> 3, part = blockIdx.x & 7;
  const float* p = attP + (size_t)(b * 128 + part * 16) * 4096;
  float* q = attQ + (size_t)(b * 8 + part) * 4096;
  for (int e = threadIdx.x; e < 4096; e += 256) {
    float s0 = 0.f, s1 = 0.f, s2 = 0.f, s3 = 0.f;
    #pragma unroll
    for (int k = 0; k < 16; k += 4) {
      s0 += p[(size_t)k * 4096 + e];
      s1 += p[(size_t)(k + 1) * 4096 + e];
      s2 += p[(size_t)(k + 2) * 4096 + e];
      s3 += p[(size_t)(k + 3) * 4096 + e];
    }
    q[e] = (s0 + s1) + (s2 + s3);
  }
}

// ---------------------------------------------------------------------------
// k3b: reduce spart (128 float2/batch) -> scale; final att reduce; N mats.
// ---------------------------------------------------------------------------
__global__ __launch_bounds__(1024) void k3b_nmat(
    const float* __restrict__ attQ, const float2* __restrict__ spart,
    const float* __restrict__ wm, const float* __restrict__ wtheta,
    unsigned short* __restrict__ Nhi, unsigned short* __restrict__ Nlo)
{
  __shared__ float att_s[4096];
  __shared__ float Mp[2][64][64];
  __shared__ float wms[64][32];
  __shared__ float wts[32][64];
  __shared__ float sP[128], sG[128];
  const int tid = threadIdx.x;
  const int b = blockIdx.x;

  if (tid < 512) {
    if (tid < 128) {
      const float2 v = spart[b * 128 + tid];
      sP[tid] = v.x; sG[tid] = v.y;
    }
    if (tid < 256) { for (int k = tid; k < 2048; k += 256) wms[k >> 5][k & 31] = wm[k]; }
    else           { for (int k = tid - 256; k < 2048; k += 256) wts[k >> 6][k & 63] = wtheta[k]; }
  }
  for (int e = tid; e < 4096; e += 1024) {
    const float* p = attQ + (size_t)b * 8 * 4096 + e;
    float s = 0.f;
    #pragma unroll
    for (int q = 0; q < 8; ++q) s += p[(size_t)q * 4096];
    att_s[e] = s;
  }
  __syncthreads();
  #pragma unroll
  for (int s = 64; s > 0; s >>= 1) {
    if (tid < s) { sP[tid] += sP[tid + s]; sG[tid] += sG[tid + s]; }
    __syncthreads();
  }
  for (int idx = tid; idx < 8192; idx += 1024) {
    const int h = idx >> 12, o = (idx >> 6) & 63, d = idx & 63;
    float s = 0.f;
    #pragma unroll
    for (int i = 0; i < 32; ++i)
      s = __builtin_fmaf(wms[o][i], att_s[(2 * i + h) * 64 + d], s);
    Mp[h][o][d] = s;
  }
  __syncthreads();
  const float scale = 1.f / (sP[0] * sG[0]);
  for (int idx = tid; idx < 16384; idx += 1024) {
    const int oo = idx >> 7, cc = idx & 127;
    const int h = oo >> 6, o = oo & 63, e = cc >> 6, c = cc & 63;
    float s = 0.f;
    #pragma unroll
    for (int j = 0; j < 32; ++j)
      s = __builtin_fmaf(Mp[h][o][2 * j + e], wts[j][c], s);
    s *= scale;
    const unsigned short hi = f2bf(s);
    Nhi[(size_t)b * 16384 + idx] = hi;
    Nlo[(size_t)b * 16384 + idx] = f2bf(s - bf2f(hi));
  }
}

// ---------------------------------------------------------------------------
// k5: out[b][o][h*NPOS+n] = sum_cc N[b][h*64+o][cc] * x[b][cc&63][(cc>>6)*NPOS+n]
// A = x [n][cc], B = N rows (oo) -> lane stores float4 of consecutive n.
// ---------------------------------------------------------------------------
__global__ __launch_bounds__(512) void k5_out(
    const float* __restrict__ x, const unsigned short* __restrict__ Nhi,
    const unsigned short* __restrict__ Nlo, float* __restrict__ out)
{
  __shared__ unsigned short Xh[64 * 128];   // [n][cc] bf16, cc ^ (slot4(n)<<3)
  const int tid = threadIdx.x;
  const int b = blockIdx.y, n0 = blockIdx.x * 64;
  const int w = tid >> 6, l = tid & 63;
  const int lr = l & 15, g = l >> 4;

  short8 bh[4], bl[4];
  #pragma unroll
  for (int ks = 0; ks < 4; ++ks) {
    const size_t off = (size_t)b * 16384 + (size_t)(w * 16 + lr) * 128 + ks * 32 + g * 8;
    bh[ks] = *(const short8*)(Nhi + off);
    bl[ks] = *(const short8*)(Nlo + off);
  }

  {
    const int ccb = w * 16;
    const int c0 = ccb & 63, e0 = ccb >> 6;
    const float* xp = x + (size_t)b * 64 * HW + (size_t)c0 * HW
                    + (size_t)e0 * NPOS + n0 + l;
    float v[16];
    #pragma unroll
    for (int i = 0; i < 16; ++i) v[i] = xp[(size_t)i * HW];
    short8 pa, pb;
    #pragma unroll
    for (int i = 0; i < 8; ++i) {
      pa[i] = (short)f2bf(v[i]);
      pb[i] = (short)f2bf(v[8 + i]);
    }
    const int s8 = slot4(l) << 3;
    *(short8*)&Xh[l * 128 + (ccb ^ s8)] = pa;
    *(short8*)&Xh[l * 128 + ((ccb + 8) ^ s8)] = pb;
  }
  __syncthreads();

  const int oo = w * 16 + lr;
  float* op = out + (size_t)b * 64 * HW + (size_t)(oo & 63) * HW
            + (size_t)(oo >> 6) * NPOS + n0 + g * 4;

  #pragma unroll
  for (int ct4 = 0; ct4 < 4; ++ct4) {
    f32x4 acc = {0.f, 0.f, 0.f, 0.f};
    const int arow = ct4 * 16 + lr;
    const int sw = slot4(arow) << 3;
    #pragma unroll
    for (int ks = 0; ks < 4; ++ks) {
      const short8 av = *(const short8*)&Xh[arow * 128 + ((ks * 32 + g * 8) ^ sw)];
      acc = __builtin_amdgcn_mfma_f32_16x16x32_bf16(av, bh[ks], acc, 0, 0, 0);
      acc = __builtin_amdgcn_mfma_f32_16x16x32_bf16(av, bl[ks], acc, 0, 0, 0);
    }
    *(float4*)(op + ct4 * 16) = *(float4*)&acc;
  }
}

// ---------------------------------------------------------------------------
extern "C" void kernel_launch(void* const* d_in, const int* in_sizes, int n_in,
                              void* d_out, int out_size, void* d_ws, size_t ws_size,
                              hipStream_t stream)
{
  const float* x      = (const float*)d_in[0];
  const float* wphi   = (const float*)d_in[1];
  const float* wtheta = (const float*)d_in[2];
  const float* wg     = (const float*)d_in[3];
  const float* wm     = (const float*)d_in[4];
  float* out = (float*)d_out;

  char* ws = (char*)d_ws;
  float* attP         = (float*)ws;                                 // 16,777,216 B
  unsigned short* Whi = (unsigned short*)(ws + 16777216);           //      8,192 B
  unsigned short* Wlo = (unsigned short*)(ws + 16785408);           //      8,192 B
  unsigned short* Nhi = (unsigned short*)(ws + 16793600);           //    262,144 B
  unsigned short* Nlo = (unsigned short*)(ws + 17055744);           //    262,144 B
  float2* spart       = (float2*)(ws + 17317888);                   //      8,192 B
  float* attQ         = (float*)(ws + 17326080);                    //  1,048,576 B

  k0_prep<<<dim3(16), 256, 0, stream>>>(wphi, wg, Whi, Wlo);
  k1_att<<<dim3(128, 8), 256, 0, stream>>>(x, Whi, Wlo, attP, spart);
  k3a_reduce<<<dim3(64), 256, 0, stream>>>(attP, attQ);
  k3b_nmat<<<dim3(8), 1024, 0, stream>>>(attQ, spart, wm, wtheta, Nhi, Nlo);
  k5_out<<<dim3(512, 8), 512, 0, stream>>>(x, Nhi, Nlo, out);
}